// Round 4
// baseline (471.148 us; speedup 1.0000x reference)
//
#include <hip/hip_runtime.h>
#include <hip/hip_bf16.h>
#include <math.h>

#define GG 2
#define NPG 332
#define NN 664
#define EE 21248
#define EPG 10624
#define KHD 6
#define KP1 166
#define KP2 83
#define DIM 332
#define DD3 128
#define MAXIN 128
#define KTOT 2324          // 7*332
#define W2ROWS 1992        // 6*332

// ---------------- prep: zero cnt1 and xt1 ----------------
__global__ void k_prep(int* __restrict__ cnt1, float* __restrict__ xt1) {
    int t = blockIdx.x * 256 + threadIdx.x;          // 128 blocks * 256
    for (int i = t; i < NN; i += 128 * 256) cnt1[i] = 0;
    for (int i = t; i < NN * DIM; i += 128 * 256) xt1[i] = 0.f;
}

// ---------------- bucket build, conv1 ----------------
__global__ void k_bucket(const int* __restrict__ dst, int* cnt, int* bucket) {
    int e = blockIdx.x * 256 + threadIdx.x;
    if (e >= EE) return;
    int d = dst[e];
    int slot = atomicAdd(&cnt[d], 1);
    if (slot < MAXIN) bucket[d * MAXIN + slot] = e;
}

// ---------------- GEMM with fused A-build:  C[M][332] += (h ⊙ X)[M][2324] @ B[2324][332] ----------------
// A[n][k*332+i] = hs[n][k] * X[n][i];  hs[n][k] = relu(W1[roi(n)][k]) (k<6), hs[n][6]=1
// B row r: r<1992 ? W2 + r*332 : nb + (r-1992)*332
#define BM 64
#define BN 64
#define BK 16
#define SPLITK 4

__global__ __launch_bounds__(256) void k_gemm(const float* __restrict__ X,
                                              const int* __restrict__ perm,
                                              const float* __restrict__ W1,
                                              const float* __restrict__ W2,
                                              const float* __restrict__ nb,
                                              float* __restrict__ C, int M) {
    __shared__ float As[BK][BM + 4];
    __shared__ float Bs[BK][BN];
    __shared__ float hs[BM][8];
    int tid = threadIdx.x;
    int tx = tid & 15, ty = tid >> 4;
    int col0 = blockIdx.x * BN, row0 = blockIdx.y * BM;
    if (tid < BM) {
        int r = row0 + tid;
        int roi = (r < M) ? ((perm ? perm[r] : r) % DIM) : 0;
        bool ok = r < M;
#pragma unroll
        for (int k = 0; k < 6; ++k)
            hs[tid][k] = ok ? fmaxf(W1[roi * KHD + k], 0.f) : 0.f;
        hs[tid][6] = ok ? 1.f : 0.f;
    }
    const int kc = (KTOT + SPLITK - 1) / SPLITK;    // 581
    int k0 = blockIdx.z * kc;
    int k1 = k0 + kc; if (k1 > KTOT) k1 = KTOT;
    float acc[4][4] = {};
    __syncthreads();
    for (int kb = k0; kb < k1; kb += BK) {
        {   // stage A: As[kk][m] = hs[m][kch] * X[row0+m][i],  kg = kb+kk = kch*332+i
            int kk = tid & 15;
            int m0 = tid >> 4;
            int kg = kb + kk;
            bool kok = kg < k1;
            int kch = kg / DIM;
            int i = kg - kch * DIM;
#pragma unroll
            for (int mi = 0; mi < 4; ++mi) {
                int mm = m0 + mi * 16;
                int r = row0 + mm;
                As[kk][mm] = (kok && r < M) ? hs[mm][kch] * X[(size_t)r * DIM + i] : 0.f;
            }
        }
        {   // stage B
            int n = tid & 63;
            int kb4 = tid >> 6;
            int c = col0 + n;
#pragma unroll
            for (int ki = 0; ki < 4; ++ki) {
                int kk = kb4 + ki * 4;
                int r = kb + kk;
                float v = 0.f;
                if (r < k1 && c < DIM) {
                    const float* Brow = (r < W2ROWS) ? (W2 + (size_t)r * DIM)
                                                     : (nb + (size_t)(r - W2ROWS) * DIM);
                    v = Brow[c];
                }
                Bs[kk][n] = v;
            }
        }
        __syncthreads();
#pragma unroll
        for (int kk = 0; kk < BK; ++kk) {
            float a[4], b[4];
#pragma unroll
            for (int i = 0; i < 4; ++i) a[i] = As[kk][ty * 4 + i];
#pragma unroll
            for (int j = 0; j < 4; ++j) b[j] = Bs[kk][tx * 4 + j];
#pragma unroll
            for (int i = 0; i < 4; ++i)
#pragma unroll
                for (int j = 0; j < 4; ++j) acc[i][j] += a[i] * b[j];
        }
        __syncthreads();
    }
#pragma unroll
    for (int i = 0; i < 4; ++i) {
        int r = row0 + ty * 4 + i;
        if (r < M) {
#pragma unroll
            for (int j = 0; j < 4; ++j) {
                int c = col0 + tx * 4 + j;
                if (c < DIM) atomicAdd(&C[(size_t)r * DIM + c], acc[i][j]);
            }
        }
    }
}

// ---------------- aggregation + bias, fused pooling score ----------------
__global__ void k_agg(const float* __restrict__ xt, const int* __restrict__ cnt,
                      const int* __restrict__ bucket, const int* __restrict__ srcArr,
                      const float* __restrict__ eattr, const int* __restrict__ newidx,
                      const float* __restrict__ bias, const float* __restrict__ w,
                      float* __restrict__ out, float* __restrict__ score) {
    __shared__ float alpha[MAXIN];
    __shared__ int sidx[MAXIN];
    __shared__ float red[256];
    __shared__ float red2[256];
    int n = blockIdx.x, t = threadIdx.x;
    int c = cnt[n]; if (c > MAXIN) c = MAXIN;
    float mysum = 0.f;
    for (int j = t; j < c; j += 256) {
        int e = bucket[n * MAXIN + j];
        int s = srcArr[e];
        if (newidx) s = newidx[s];
        float ex = expf(eattr[e]);
        alpha[j] = ex;
        sidx[j] = s;
        mysum += ex;
    }
    red[t] = mysum;
    __syncthreads();
    for (int off = 128; off > 0; off >>= 1) {
        if (t < off) red[t] += red[t + off];
        __syncthreads();
    }
    const float eself = 2.718281828459045f;
    float inv = 1.f / (red[0] + eself);
    __syncthreads();
    for (int j = t; j < c; j += 256) alpha[j] *= inv;
    __syncthreads();
    float aself = eself * inv;
    float dotp = 0.f, wsq = 0.f;
    for (int o = t; o < DIM; o += 256) {
        float acc = bias[o] + aself * xt[(size_t)n * DIM + o];
        for (int j = 0; j < c; ++j) acc += alpha[j] * xt[(size_t)sidx[j] * DIM + o];
        out[(size_t)n * DIM + o] = acc;
        float wv = w[o];
        dotp += acc * wv;
        wsq += wv * wv;
    }
    red[t] = dotp; red2[t] = wsq;
    __syncthreads();
    for (int off = 128; off > 0; off >>= 1) {
        if (t < off) { red[t] += red[t + off]; red2[t] += red2[t + off]; }
        __syncthreads();
    }
    if (t == 0) score[n] = 1.f / (1.f + expf(-red[0] / sqrtf(red2[0])));
}

// ---------------- top-k rank + (level1) bucket2 build; also zeroes next accumulators ----------------
__global__ void k_topk(const float* __restrict__ score, int n_per, int k,
                       int* __restrict__ perm, int* __restrict__ newidx,
                       const int* __restrict__ src, const int* __restrict__ dst,
                       int* __restrict__ cnt2, int* __restrict__ bucket2,
                       float* __restrict__ fz1, int fn1,
                       float* __restrict__ fz2, int fn2) {
    __shared__ float s[NPG];
    __shared__ short nidxS[NPG];
    int g = blockIdx.x, t = threadIdx.x;     // 2 blocks x 384
    for (int i = t; i < n_per; i += 384) s[i] = score[g * n_per + i];
    if (cnt2) for (int i = t; i < k; i += 384) cnt2[g * k + i] = 0;
    if (fz1) for (int i = g * 384 + t; i < fn1; i += GG * 384) fz1[i] = 0.f;
    if (fz2) for (int i = g * 384 + t; i < fn2; i += GG * 384) fz2[i] = 0.f;
    __syncthreads();
    for (int i = t; i < n_per; i += 384) {
        float si = s[i];
        int r = 0;
        for (int j = 0; j < n_per; ++j) {
            float sj = s[j];
            r += (sj > si) || (sj == si && j < i);
        }
        int node = g * n_per + i;
        if (r < k) {
            perm[g * k + r] = node;
            newidx[node] = g * k + r;
            nidxS[i] = (short)(g * k + r);
        } else {
            newidx[node] = -1;
            nidxS[i] = -1;
        }
    }
    if (cnt2) {
        __syncthreads();
        int e0 = g * EPG;
        for (int e = e0 + t; e < e0 + EPG; e += 384) {
            int ns = nidxS[src[e] - g * n_per];
            int nd = nidxS[dst[e] - g * n_per];
            if (ns >= 0 && nd >= 0) {
                int slot = atomicAdd(&cnt2[nd], 1);
                if (slot < MAXIN) bucket2[nd * MAXIN + slot] = e;
            }
        }
    }
}

// ---------------- gather: xnew (optional) + readout max/mean, column-parallel ----------------
__global__ void k_gather(const float* __restrict__ xv, const float* __restrict__ score,
                         const int* __restrict__ perm, int k,
                         float* __restrict__ xnew, float* __restrict__ z, int zbase) {
    int g = blockIdx.y;
    int o = blockIdx.x * 256 + threadIdx.x;
    if (o >= DIM) return;
    float mx = -3.4e38f, sm = 0.f;
    for (int r = 0; r < k; ++r) {
        int p = perm[g * k + r];
        float v = xv[(size_t)p * DIM + o] * score[p];
        if (xnew) xnew[(size_t)(g * k + r) * DIM + o] = v;
        mx = fmaxf(mx, v);
        sm += v;
    }
    z[(size_t)g * 1328 + zbase + o] = mx;
    z[(size_t)g * 1328 + zbase + DIM + o] = sm / (float)k;
}

// ---------------- fc1 partials ----------------
__global__ void k_fc1(const float* __restrict__ z, const float* __restrict__ W,
                      float* __restrict__ hacc) {
    __shared__ float zs[2][166];
    int t = threadIdx.x;                 // 128
    int j = blockIdx.x * 128 + t;
    int i0 = blockIdx.y * 166;
    for (int i = t; i < 166; i += 128) {
        zs[0][i] = z[i0 + i];
        zs[1][i] = z[1328 + i0 + i];
    }
    __syncthreads();
    if (j >= DIM) return;
    float a0 = 0.f, a1 = 0.f;
    for (int i = 0; i < 166; ++i) {
        float wv = W[(size_t)(i0 + i) * DIM + j];
        a0 += zs[0][i] * wv;
        a1 += zs[1][i] * wv;
    }
    atomicAdd(&hacc[j], a0);
    atomicAdd(&hacc[DIM + j], a1);
}

// ---------------- fc2 partials: BN1+relu on chunk, then partial fc2 ----------------
__global__ void k_fc2(const float* __restrict__ hacc, const float* __restrict__ fc1b,
                      const float* __restrict__ bn1g, const float* __restrict__ bn1b,
                      const float* __restrict__ W, float* __restrict__ f2acc) {
    __shared__ float z1s[2][83];
    int t = threadIdx.x;                 // 128
    int i0 = blockIdx.x * 83;
    if (t < 83) {
        int col = i0 + t;
        float a0 = hacc[col] + fc1b[col];
        float a1 = hacc[DIM + col] + fc1b[col];
        float m = 0.5f * (a0 + a1);
        float d0 = a0 - m, d1 = a1 - m;
        float v = 0.5f * (d0 * d0 + d1 * d1);
        float is = 1.f / sqrtf(v + 1e-5f);
        float gj = bn1g[col], bj = bn1b[col];
        z1s[0][t] = fmaxf(d0 * is * gj + bj, 0.f);
        z1s[1][t] = fmaxf(d1 * is * gj + bj, 0.f);
    }
    __syncthreads();
    float a0 = 0.f, a1 = 0.f;
    for (int i = 0; i < 83; ++i) {
        float wv = W[(size_t)(i0 + i) * DD3 + t];
        a0 += z1s[0][i] * wv;
        a1 += z1s[1][i] * wv;
    }
    atomicAdd(&f2acc[t], a0);
    atomicAdd(&f2acc[DD3 + t], a1);
}

// ---------------- final: BN2+relu+fc3 ----------------
__global__ void k_head3(const float* __restrict__ f2acc, const float* __restrict__ fc2b,
                        const float* __restrict__ bn2g, const float* __restrict__ bn2b,
                        const float* __restrict__ fc3W, const float* __restrict__ fc3b,
                        float* __restrict__ out) {
    __shared__ float z2s[2][DD3];
    int t = threadIdx.x;                 // 128
    {
        float a0 = f2acc[t] + fc2b[t];
        float a1 = f2acc[DD3 + t] + fc2b[t];
        float m = 0.5f * (a0 + a1);
        float d0 = a0 - m, d1 = a1 - m;
        float v = 0.5f * (d0 * d0 + d1 * d1);
        float is = 1.f / sqrtf(v + 1e-5f);
        float gj = bn2g[t], bj = bn2b[t];
        z2s[0][t] = fmaxf(d0 * is * gj + bj, 0.f);
        z2s[1][t] = fmaxf(d1 * is * gj + bj, 0.f);
    }
    __syncthreads();
    if (t < 4) {
        int g = t >> 1, c = t & 1;
        float acc = fc3b[c];
        for (int i = 0; i < DD3; ++i) acc += z2s[g][i] * fc3W[i * 2 + c];
        out[g * 2 + c] = acc;
    }
}

extern "C" void kernel_launch(void* const* d_in, const int* in_sizes, int n_in,
                              void* d_out, int out_size, void* d_ws, size_t ws_size,
                              hipStream_t stream) {
    (void)in_sizes; (void)n_in; (void)out_size; (void)ws_size;
    const float* x     = (const float*)d_in[0];
    const int*   eidx  = (const int*)d_in[1];
    const float* eattr = (const float*)d_in[3];
    const float* c1W1  = (const float*)d_in[6];
    const float* c1W2  = (const float*)d_in[7];
    const float* c1nb  = (const float*)d_in[8];
    const float* c1b   = (const float*)d_in[9];
    const float* p1w   = (const float*)d_in[10];
    const float* c2W1  = (const float*)d_in[11];
    const float* c2W2  = (const float*)d_in[12];
    const float* c2nb  = (const float*)d_in[13];
    const float* c2b   = (const float*)d_in[14];
    const float* p2w   = (const float*)d_in[15];
    const float* fc1W  = (const float*)d_in[16];
    const float* fc1b  = (const float*)d_in[17];
    const float* bn1g  = (const float*)d_in[18];
    const float* bn1b  = (const float*)d_in[19];
    const float* fc2W  = (const float*)d_in[20];
    const float* fc2b  = (const float*)d_in[21];
    const float* bn2g  = (const float*)d_in[22];
    const float* bn2b  = (const float*)d_in[23];
    const float* fc3W  = (const float*)d_in[24];
    const float* fc3b  = (const float*)d_in[25];

    const int* src = eidx;
    const int* dst = eidx + EE;

    char* w = (char*)d_ws;
    auto alloc = [&](size_t bytes) { void* p = (void*)w; w += ((bytes + 255) / 256) * 256; return p; };
    int*   cnt1    = (int*)alloc(NN * 4);
    int*   bucket1 = (int*)alloc((size_t)NN * MAXIN * 4);
    float* xt1     = (float*)alloc((size_t)NN * DIM * 4);
    float* out1    = (float*)alloc((size_t)NN * DIM * 4);
    float* score1  = (float*)alloc(NN * 4);
    int*   perm1   = (int*)alloc(GG * KP1 * 4);
    int*   newidx1 = (int*)alloc(NN * 4);
    float* x1p     = (float*)alloc((size_t)GG * KP1 * DIM * 4);
    float* zbuf    = (float*)alloc(GG * 1328 * 4);
    int*   cnt2    = (int*)alloc(GG * KP1 * 4);
    int*   bucket2 = (int*)alloc((size_t)GG * KP1 * MAXIN * 4);
    float* xt2     = (float*)alloc((size_t)GG * KP1 * DIM * 4);
    float* out2    = (float*)alloc((size_t)GG * KP1 * DIM * 4);
    float* score2  = (float*)alloc(GG * KP1 * 4);
    int*   perm2   = (int*)alloc(GG * KP2 * 4);
    int*   newidx2 = (int*)alloc(GG * KP1 * 4);
    float* hacc    = (float*)alloc(2 * DIM * 4);
    float* f2acc   = (float*)alloc(2 * DD3 * 4);

    // ---- conv1 ----
    k_prep<<<128, 256, 0, stream>>>(cnt1, xt1);
    k_bucket<<<(EE + 255) / 256, 256, 0, stream>>>(dst, cnt1, bucket1);
    k_gemm<<<dim3(6, 11, SPLITK), 256, 0, stream>>>(x, nullptr, c1W1, c1W2, c1nb, xt1, NN);
    k_agg<<<NN, 256, 0, stream>>>(xt1, cnt1, bucket1, src, eattr, nullptr, c1b, p1w, out1, score1);

    // ---- pool1 (+ bucket2 build + zero cnt2/xt2) ----
    k_topk<<<GG, 384, 0, stream>>>(score1, NPG, KP1, perm1, newidx1,
                                   src, dst, cnt2, bucket2,
                                   xt2, GG * KP1 * DIM, nullptr, 0);
    k_gather<<<dim3(2, GG), 256, 0, stream>>>(out1, score1, perm1, KP1, x1p, zbuf, 0);

    // ---- conv2 ----
    k_gemm<<<dim3(6, 6, SPLITK), 256, 0, stream>>>(x1p, perm1, c2W1, c2W2, c2nb, xt2, GG * KP1);
    k_agg<<<GG * KP1, 256, 0, stream>>>(xt2, cnt2, bucket2, src, eattr, newidx1, c2b, p2w, out2, score2);

    // ---- pool2 (+ zero hacc/f2acc) ----
    k_topk<<<GG, 384, 0, stream>>>(score2, KP1, KP2, perm2, newidx2,
                                   nullptr, nullptr, nullptr, nullptr,
                                   hacc, 2 * DIM, f2acc, 2 * DD3);
    k_gather<<<dim3(2, GG), 256, 0, stream>>>(out2, score2, perm2, KP2, nullptr, zbuf, 664);

    // ---- head ----
    k_fc1<<<dim3(3, 8), 128, 0, stream>>>(zbuf, fc1W, hacc);
    k_fc2<<<4, 128, 0, stream>>>(hacc, fc1b, bn1g, bn1b, fc2W, f2acc);
    k_head3<<<1, 128, 0, stream>>>(f2acc, fc2b, bn2g, bn2b, fc3W, fc3b, (float*)d_out);
}

// Round 8
// 411.801 us; speedup vs baseline: 1.1441x; 1.1441x over previous
//
#include <hip/hip_runtime.h>
#include <hip/hip_bf16.h>
#include <math.h>

#define GG 2
#define NPG 332
#define NN 664
#define EE 21248
#define EPG 10624
#define KHD 6
#define KP1 166
#define KP2 83
#define DIM 332
#define DD3 128
#define MAXIN 128
#define KTOT 2324          // 7*332
#define W2ROWS 1992        // 6*332

// ---------------- prep: zero cnt1 and xt1 ----------------
__global__ void k_prep(int* __restrict__ cnt1, float* __restrict__ xt1) {
    int t = blockIdx.x * 256 + threadIdx.x;          // 128 blocks * 256
    for (int i = t; i < NN; i += 128 * 256) cnt1[i] = 0;
    for (int i = t; i < NN * DIM; i += 128 * 256) xt1[i] = 0.f;
}

// ---------------- bucket build, conv1 ----------------
__global__ void k_bucket(const int* __restrict__ dst, int* cnt, int* bucket) {
    int e = blockIdx.x * 256 + threadIdx.x;
    if (e >= EE) return;
    int d = dst[e];
    int slot = atomicAdd(&cnt[d], 1);
    if (slot < MAXIN) bucket[d * MAXIN + slot] = e;
}

// ---------------- GEMM with fused A-build, reg-prefetch pipeline ----------------
// C[M][332] += (h ⊙ X)[M][2324] @ B[2324][332]
// A[n][k*332+i] = hs[n][k]*X[n][i];  hs[n][k] = relu(W1[roi(n)][k]) (k<6), hs[n][6]=1
// B row r: r<1992 ? W2 + r*332 : nb + (r-1992)*332
#define BM 64
#define BN 64
#define BK 16
#define SPLITK 16

__global__ __launch_bounds__(256) void k_gemm(const float* __restrict__ X,
                                              const int* __restrict__ perm,
                                              const float* __restrict__ W1,
                                              const float* __restrict__ W2,
                                              const float* __restrict__ nb,
                                              float* __restrict__ C, int M) {
    __shared__ float As[BK][BM + 4];
    __shared__ float Bs[BK][BN];
    __shared__ float hs[BM][8];
    int tid = threadIdx.x;
    int tx = tid & 15, ty = tid >> 4;
    int col0 = blockIdx.x * BN, row0 = blockIdx.y * BM;
    if (tid < BM) {
        int r = row0 + tid;
        int roi = (r < M) ? ((perm ? perm[r] : r) % DIM) : 0;
        bool ok = r < M;
#pragma unroll
        for (int k = 0; k < 6; ++k)
            hs[tid][k] = ok ? fmaxf(W1[roi * KHD + k], 0.f) : 0.f;
        hs[tid][6] = ok ? 1.f : 0.f;
        hs[tid][7] = 0.f;
    }
    const int kc = (KTOT + SPLITK - 1) / SPLITK;    // 146
    int k0 = blockIdx.z * kc;
    int k1 = k0 + kc; if (k1 > KTOT) k1 = KTOT;
    __syncthreads();                                 // hs ready

    // staging lane roles
    int kkA = tid & 15;          // A: k within tile
    int m0A = tid >> 4;          // A: row group 0..15
    int nB  = tid & 63;          // B: col within tile
    int kB0 = tid >> 6;          // B: k group 0..3

    float aReg[4], bReg[4];
    auto loadAB = [&](int kb) {
        {
            int kg = kb + kkA;
            bool kok = kg < k1;
            int kch = kg / DIM;
            int i = kg - kch * DIM;
#pragma unroll
            for (int mi = 0; mi < 4; ++mi) {
                int mm = m0A + mi * 16;
                int r = row0 + mm;
                aReg[mi] = (kok && r < M) ? hs[mm][kch] * X[(size_t)r * DIM + i] : 0.f;
            }
        }
        {
            int c = col0 + nB;
#pragma unroll
            for (int ki = 0; ki < 4; ++ki) {
                int r = kb + kB0 + ki * 4;
                float v = 0.f;
                if (r < k1 && c < DIM) {
                    const float* Brow = (r < W2ROWS) ? (W2 + (size_t)r * DIM)
                                                     : (nb + (size_t)(r - W2ROWS) * DIM);
                    v = Brow[c];
                }
                bReg[ki] = v;
            }
        }
    };
    auto writeAB = [&]() {
#pragma unroll
        for (int mi = 0; mi < 4; ++mi) As[kkA][m0A + mi * 16] = aReg[mi];
#pragma unroll
        for (int ki = 0; ki < 4; ++ki) Bs[kB0 + ki * 4][nB] = bReg[ki];
    };

    float acc[4][4] = {};
    loadAB(k0);
    writeAB();
    __syncthreads();
    for (int kb = k0; kb < k1; kb += BK) {
        int kn = kb + BK;
        bool more = kn < k1;
        if (more) loadAB(kn);            // prefetch: in flight during compute
#pragma unroll
        for (int kk = 0; kk < BK; ++kk) {
            float a[4], b[4];
#pragma unroll
            for (int i = 0; i < 4; ++i) a[i] = As[kk][ty * 4 + i];
#pragma unroll
            for (int j = 0; j < 4; ++j) b[j] = Bs[kk][tx * 4 + j];
#pragma unroll
            for (int i = 0; i < 4; ++i)
#pragma unroll
                for (int j = 0; j < 4; ++j) acc[i][j] += a[i] * b[j];
        }
        __syncthreads();
        if (more) {
            writeAB();
            __syncthreads();
        }
    }
#pragma unroll
    for (int i = 0; i < 4; ++i) {
        int r = row0 + ty * 4 + i;
        if (r < M) {
#pragma unroll
            for (int j = 0; j < 4; ++j) {
                int c = col0 + tx * 4 + j;
                if (c < DIM) atomicAdd(&C[(size_t)r * DIM + c], acc[i][j]);
            }
        }
    }
}

// ---------------- aggregation + bias, fused pooling score ----------------
__global__ void k_agg(const float* __restrict__ xt, const int* __restrict__ cnt,
                      const int* __restrict__ bucket, const int* __restrict__ srcArr,
                      const float* __restrict__ eattr, const int* __restrict__ newidx,
                      const float* __restrict__ bias, const float* __restrict__ w,
                      float* __restrict__ out, float* __restrict__ score) {
    __shared__ float alpha[MAXIN];
    __shared__ int sidx[MAXIN];
    __shared__ float red[256];
    __shared__ float red2[256];
    int n = blockIdx.x, t = threadIdx.x;
    int c = cnt[n]; if (c > MAXIN) c = MAXIN;
    float mysum = 0.f;
    for (int j = t; j < c; j += 256) {
        int e = bucket[n * MAXIN + j];
        int s = srcArr[e];
        if (newidx) s = newidx[s];
        float ex = expf(eattr[e]);
        alpha[j] = ex;
        sidx[j] = s;
        mysum += ex;
    }
    red[t] = mysum;
    __syncthreads();
    for (int off = 128; off > 0; off >>= 1) {
        if (t < off) red[t] += red[t + off];
        __syncthreads();
    }
    const float eself = 2.718281828459045f;
    float inv = 1.f / (red[0] + eself);
    __syncthreads();
    for (int j = t; j < c; j += 256) alpha[j] *= inv;
    __syncthreads();
    float aself = eself * inv;
    float dotp = 0.f, wsq = 0.f;
    for (int o = t; o < DIM; o += 256) {
        float acc = bias[o] + aself * xt[(size_t)n * DIM + o];
        for (int j = 0; j < c; ++j) acc += alpha[j] * xt[(size_t)sidx[j] * DIM + o];
        out[(size_t)n * DIM + o] = acc;
        float wv = w[o];
        dotp += acc * wv;
        wsq += wv * wv;
    }
    red[t] = dotp; red2[t] = wsq;
    __syncthreads();
    for (int off = 128; off > 0; off >>= 1) {
        if (t < off) { red[t] += red[t + off]; red2[t] += red2[t + off]; }
        __syncthreads();
    }
    if (t == 0) score[n] = 1.f / (1.f + expf(-red[0] / sqrtf(red2[0])));
}

// ---------------- top-k rank + (level1) bucket2 build; also zeroes next accumulators ----------------
__global__ void k_topk(const float* __restrict__ score, int n_per, int k,
                       int* __restrict__ perm, int* __restrict__ newidx,
                       const int* __restrict__ src, const int* __restrict__ dst,
                       int* __restrict__ cnt2, int* __restrict__ bucket2,
                       float* __restrict__ fz1, int fn1,
                       float* __restrict__ fz2, int fn2) {
    __shared__ float s[NPG];
    __shared__ short nidxS[NPG];
    int g = blockIdx.x, t = threadIdx.x;     // 2 blocks x 384
    for (int i = t; i < n_per; i += 384) s[i] = score[g * n_per + i];
    if (cnt2) for (int i = t; i < k; i += 384) cnt2[g * k + i] = 0;
    if (fz1) for (int i = g * 384 + t; i < fn1; i += GG * 384) fz1[i] = 0.f;
    if (fz2) for (int i = g * 384 + t; i < fn2; i += GG * 384) fz2[i] = 0.f;
    __syncthreads();
    for (int i = t; i < n_per; i += 384) {
        float si = s[i];
        int r = 0;
        for (int j = 0; j < n_per; ++j) {
            float sj = s[j];
            r += (sj > si) || (sj == si && j < i);
        }
        int node = g * n_per + i;
        if (r < k) {
            perm[g * k + r] = node;
            newidx[node] = g * k + r;
            nidxS[i] = (short)(g * k + r);
        } else {
            newidx[node] = -1;
            nidxS[i] = -1;
        }
    }
    if (cnt2) {
        __syncthreads();
        int e0 = g * EPG;
        for (int e = e0 + t; e < e0 + EPG; e += 384) {
            int ns = nidxS[src[e] - g * n_per];
            int nd = nidxS[dst[e] - g * n_per];
            if (ns >= 0 && nd >= 0) {
                int slot = atomicAdd(&cnt2[nd], 1);
                if (slot < MAXIN) bucket2[nd * MAXIN + slot] = e;
            }
        }
    }
}

// ---------------- gather: xnew (optional) + readout max/mean, column-parallel ----------------
__global__ void k_gather(const float* __restrict__ xv, const float* __restrict__ score,
                         const int* __restrict__ perm, int k,
                         float* __restrict__ xnew, float* __restrict__ z, int zbase) {
    int g = blockIdx.y;
    int o = blockIdx.x * 256 + threadIdx.x;
    if (o >= DIM) return;
    float mx = -3.4e38f, sm = 0.f;
    for (int r = 0; r < k; ++r) {
        int p = perm[g * k + r];
        float v = xv[(size_t)p * DIM + o] * score[p];
        if (xnew) xnew[(size_t)(g * k + r) * DIM + o] = v;
        mx = fmaxf(mx, v);
        sm += v;
    }
    z[(size_t)g * 1328 + zbase + o] = mx;
    z[(size_t)g * 1328 + zbase + DIM + o] = sm / (float)k;
}

// ---------------- fc1 partials ----------------
__global__ void k_fc1(const float* __restrict__ z, const float* __restrict__ W,
                      float* __restrict__ hacc) {
    __shared__ float zs[2][166];
    int t = threadIdx.x;                 // 128
    int j = blockIdx.x * 128 + t;
    int i0 = blockIdx.y * 166;
    for (int i = t; i < 166; i += 128) {
        zs[0][i] = z[i0 + i];
        zs[1][i] = z[1328 + i0 + i];
    }
    __syncthreads();
    if (j >= DIM) return;
    float a0 = 0.f, a1 = 0.f;
    for (int i = 0; i < 166; ++i) {
        float wv = W[(size_t)(i0 + i) * DIM + j];
        a0 += zs[0][i] * wv;
        a1 += zs[1][i] * wv;
    }
    atomicAdd(&hacc[j], a0);
    atomicAdd(&hacc[DIM + j], a1);
}

// ---------------- fc2 partials: BN1+relu on chunk, then partial fc2 ----------------
__global__ void k_fc2(const float* __restrict__ hacc, const float* __restrict__ fc1b,
                      const float* __restrict__ bn1g, const float* __restrict__ bn1b,
                      const float* __restrict__ W, float* __restrict__ f2acc) {
    __shared__ float z1s[2][83];
    int t = threadIdx.x;                 // 128
    int i0 = blockIdx.x * 83;
    if (t < 83) {
        int col = i0 + t;
        float a0 = hacc[col] + fc1b[col];
        float a1 = hacc[DIM + col] + fc1b[col];
        float m = 0.5f * (a0 + a1);
        float d0 = a0 - m, d1 = a1 - m;
        float v = 0.5f * (d0 * d0 + d1 * d1);
        float is = 1.f / sqrtf(v + 1e-5f);
        float gj = bn1g[col], bj = bn1b[col];
        z1s[0][t] = fmaxf(d0 * is * gj + bj, 0.f);
        z1s[1][t] = fmaxf(d1 * is * gj + bj, 0.f);
    }
    __syncthreads();
    float a0 = 0.f, a1 = 0.f;
    for (int i = 0; i < 83; ++i) {
        float wv = W[(size_t)(i0 + i) * DD3 + t];
        a0 += z1s[0][i] * wv;
        a1 += z1s[1][i] * wv;
    }
    atomicAdd(&f2acc[t], a0);
    atomicAdd(&f2acc[DD3 + t], a1);
}

// ---------------- final: BN2+relu+fc3 ----------------
__global__ void k_head3(const float* __restrict__ f2acc, const float* __restrict__ fc2b,
                        const float* __restrict__ bn2g, const float* __restrict__ bn2b,
                        const float* __restrict__ fc3W, const float* __restrict__ fc3b,
                        float* __restrict__ out) {
    __shared__ float z2s[2][DD3];
    int t = threadIdx.x;                 // 128
    {
        float a0 = f2acc[t] + fc2b[t];
        float a1 = f2acc[DD3 + t] + fc2b[t];
        float m = 0.5f * (a0 + a1);
        float d0 = a0 - m, d1 = a1 - m;
        float v = 0.5f * (d0 * d0 + d1 * d1);
        float is = 1.f / sqrtf(v + 1e-5f);
        float gj = bn2g[t], bj = bn2b[t];
        z2s[0][t] = fmaxf(d0 * is * gj + bj, 0.f);
        z2s[1][t] = fmaxf(d1 * is * gj + bj, 0.f);
    }
    __syncthreads();
    if (t < 4) {
        int g = t >> 1, c = t & 1;
        float acc = fc3b[c];
        for (int i = 0; i < DD3; ++i) acc += z2s[g][i] * fc3W[i * 2 + c];
        out[g * 2 + c] = acc;
    }
}

extern "C" void kernel_launch(void* const* d_in, const int* in_sizes, int n_in,
                              void* d_out, int out_size, void* d_ws, size_t ws_size,
                              hipStream_t stream) {
    (void)in_sizes; (void)n_in; (void)out_size; (void)ws_size;
    const float* x     = (const float*)d_in[0];
    const int*   eidx  = (const int*)d_in[1];
    const float* eattr = (const float*)d_in[3];
    const float* c1W1  = (const float*)d_in[6];
    const float* c1W2  = (const float*)d_in[7];
    const float* c1nb  = (const float*)d_in[8];
    const float* c1b   = (const float*)d_in[9];
    const float* p1w   = (const float*)d_in[10];
    const float* c2W1  = (const float*)d_in[11];
    const float* c2W2  = (const float*)d_in[12];
    const float* c2nb  = (const float*)d_in[13];
    const float* c2b   = (const float*)d_in[14];
    const float* p2w   = (const float*)d_in[15];
    const float* fc1W  = (const float*)d_in[16];
    const float* fc1b  = (const float*)d_in[17];
    const float* bn1g  = (const float*)d_in[18];
    const float* bn1b  = (const float*)d_in[19];
    const float* fc2W  = (const float*)d_in[20];
    const float* fc2b  = (const float*)d_in[21];
    const float* bn2g  = (const float*)d_in[22];
    const float* bn2b  = (const float*)d_in[23];
    const float* fc3W  = (const float*)d_in[24];
    const float* fc3b  = (const float*)d_in[25];

    const int* src = eidx;
    const int* dst = eidx + EE;

    char* w = (char*)d_ws;
    auto alloc = [&](size_t bytes) { void* p = (void*)w; w += ((bytes + 255) / 256) * 256; return p; };
    int*   cnt1    = (int*)alloc(NN * 4);
    int*   bucket1 = (int*)alloc((size_t)NN * MAXIN * 4);
    float* xt1     = (float*)alloc((size_t)NN * DIM * 4);
    float* out1    = (float*)alloc((size_t)NN * DIM * 4);
    float* score1  = (float*)alloc(NN * 4);
    int*   perm1   = (int*)alloc(GG * KP1 * 4);
    int*   newidx1 = (int*)alloc(NN * 4);
    float* x1p     = (float*)alloc((size_t)GG * KP1 * DIM * 4);
    float* zbuf    = (float*)alloc(GG * 1328 * 4);
    int*   cnt2    = (int*)alloc(GG * KP1 * 4);
    int*   bucket2 = (int*)alloc((size_t)GG * KP1 * MAXIN * 4);
    float* xt2     = (float*)alloc((size_t)GG * KP1 * DIM * 4);
    float* out2    = (float*)alloc((size_t)GG * KP1 * DIM * 4);
    float* score2  = (float*)alloc(GG * KP1 * 4);
    int*   perm2   = (int*)alloc(GG * KP2 * 4);
    int*   newidx2 = (int*)alloc(GG * KP1 * 4);
    float* hacc    = (float*)alloc(2 * DIM * 4);
    float* f2acc   = (float*)alloc(2 * DD3 * 4);

    // ---- conv1 ----
    k_prep<<<128, 256, 0, stream>>>(cnt1, xt1);
    k_bucket<<<(EE + 255) / 256, 256, 0, stream>>>(dst, cnt1, bucket1);
    k_gemm<<<dim3(6, 11, SPLITK), 256, 0, stream>>>(x, nullptr, c1W1, c1W2, c1nb, xt1, NN);
    k_agg<<<NN, 256, 0, stream>>>(xt1, cnt1, bucket1, src, eattr, nullptr, c1b, p1w, out1, score1);

    // ---- pool1 (+ bucket2 build + zero cnt2/xt2) ----
    k_topk<<<GG, 384, 0, stream>>>(score1, NPG, KP1, perm1, newidx1,
                                   src, dst, cnt2, bucket2,
                                   xt2, GG * KP1 * DIM, nullptr, 0);
    k_gather<<<dim3(2, GG), 256, 0, stream>>>(out1, score1, perm1, KP1, x1p, zbuf, 0);

    // ---- conv2 ----
    k_gemm<<<dim3(6, 6, SPLITK), 256, 0, stream>>>(x1p, perm1, c2W1, c2W2, c2nb, xt2, GG * KP1);
    k_agg<<<GG * KP1, 256, 0, stream>>>(xt2, cnt2, bucket2, src, eattr, newidx1, c2b, p2w, out2, score2);

    // ---- pool2 (+ zero hacc/f2acc) ----
    k_topk<<<GG, 384, 0, stream>>>(score2, KP1, KP2, perm2, newidx2,
                                   nullptr, nullptr, nullptr, nullptr,
                                   hacc, 2 * DIM, f2acc, 2 * DD3);
    k_gather<<<dim3(2, GG), 256, 0, stream>>>(out2, score2, perm2, KP2, nullptr, zbuf, 664);

    // ---- head ----
    k_fc1<<<dim3(3, 8), 128, 0, stream>>>(zbuf, fc1W, hacc);
    k_fc2<<<4, 128, 0, stream>>>(hacc, fc1b, bn1g, bn1b, fc2W, f2acc);
    k_head3<<<1, 128, 0, stream>>>(f2acc, fc2b, bn2g, bn2b, fc3W, fc3b, (float*)d_out);
}

// Round 9
// 345.908 us; speedup vs baseline: 1.3621x; 1.1905x over previous
//
#include <hip/hip_runtime.h>
#include <hip/hip_bf16.h>
#include <math.h>

#define GG 2
#define NPG 332
#define NN 664
#define EE 21248
#define EPG 10624
#define KHD 6
#define KP1 166
#define KP2 83
#define DIM 332
#define DD3 128
#define MAXIN 128
#define KTOT 2324          // 7*332
#define W2ROWS 1992        // 6*332
#define PLD 336            // padded partial-C leading dim
#define PROWS 704          // padded partial-C rows

// ---------------- bucket build conv1: per-graph LDS counting (replaces prep+bucket) ----------------
__global__ void k_bucket1(const int* __restrict__ dst, int* __restrict__ cnt, int* __restrict__ bucket) {
    __shared__ int lcnt[NPG];
    int g = blockIdx.x, t = threadIdx.x;        // 2 blocks x 384
    for (int i = t; i < NPG; i += 384) lcnt[i] = 0;
    __syncthreads();
    int e0 = g * EPG;
    for (int e = e0 + t; e < e0 + EPG; e += 384) {
        int dl = dst[e] - g * NPG;
        int slot = atomicAdd(&lcnt[dl], 1);
        if (slot < MAXIN) bucket[(size_t)(g * NPG + dl) * MAXIN + slot] = e;
    }
    __syncthreads();
    for (int i = t; i < NPG; i += 384) cnt[g * NPG + i] = lcnt[i];
}

// ---------------- GEMM, fused A-build, reg-prefetch, PLAIN partial stores ----------------
// P[z][r][c] = partial of C[M][332] = (h ⊙ X)[M][2324] @ B[2324][332] over K-slice z
#define BM 64
#define BN 64
#define BK 16
#define SPLITK 16

__global__ __launch_bounds__(256) void k_gemm(const float* __restrict__ X,
                                              const int* __restrict__ perm,
                                              const float* __restrict__ W1,
                                              const float* __restrict__ W2,
                                              const float* __restrict__ nb,
                                              float* __restrict__ P, int M) {
    __shared__ float As[BK][BM + 4];
    __shared__ float Bs[BK][BN];
    __shared__ float hs[BM][8];
    int tid = threadIdx.x;
    int tx = tid & 15, ty = tid >> 4;
    int col0 = blockIdx.x * BN, row0 = blockIdx.y * BM;
    if (tid < BM) {
        int r = row0 + tid;
        int roi = (r < M) ? ((perm ? perm[r] : r) % DIM) : 0;
        bool ok = r < M;
#pragma unroll
        for (int k = 0; k < 6; ++k)
            hs[tid][k] = ok ? fmaxf(W1[roi * KHD + k], 0.f) : 0.f;
        hs[tid][6] = ok ? 1.f : 0.f;
        hs[tid][7] = 0.f;
    }
    const int kc = (KTOT + SPLITK - 1) / SPLITK;    // 146
    int k0 = blockIdx.z * kc;
    int k1 = k0 + kc; if (k1 > KTOT) k1 = KTOT;
    __syncthreads();                                 // hs ready

    int kkA = tid & 15;          // A: k within tile
    int m0A = tid >> 4;          // A: row group 0..15
    int nB  = tid & 63;          // B: col within tile
    int kB0 = tid >> 6;          // B: k group 0..3

    float aReg[4], bReg[4];
    auto loadAB = [&](int kb) {
        {
            int kg = kb + kkA;
            bool kok = kg < k1;
            int kch = kg / DIM;
            int i = kg - kch * DIM;
#pragma unroll
            for (int mi = 0; mi < 4; ++mi) {
                int mm = m0A + mi * 16;
                int r = row0 + mm;
                aReg[mi] = (kok && r < M) ? hs[mm][kch] * X[(size_t)r * DIM + i] : 0.f;
            }
        }
        {
            int c = col0 + nB;
#pragma unroll
            for (int ki = 0; ki < 4; ++ki) {
                int r = kb + kB0 + ki * 4;
                float v = 0.f;
                if (r < k1 && c < DIM) {
                    const float* Brow = (r < W2ROWS) ? (W2 + (size_t)r * DIM)
                                                     : (nb + (size_t)(r - W2ROWS) * DIM);
                    v = Brow[c];
                }
                bReg[ki] = v;
            }
        }
    };
    auto writeAB = [&]() {
#pragma unroll
        for (int mi = 0; mi < 4; ++mi) As[kkA][m0A + mi * 16] = aReg[mi];
#pragma unroll
        for (int ki = 0; ki < 4; ++ki) Bs[kB0 + ki * 4][nB] = bReg[ki];
    };

    float acc[4][4] = {};
    loadAB(k0);
    writeAB();
    __syncthreads();
    for (int kb = k0; kb < k1; kb += BK) {
        int kn = kb + BK;
        bool more = kn < k1;
        if (more) loadAB(kn);            // prefetch in flight during compute
#pragma unroll
        for (int kk = 0; kk < BK; ++kk) {
            float a[4], b[4];
#pragma unroll
            for (int i = 0; i < 4; ++i) a[i] = As[kk][ty * 4 + i];
#pragma unroll
            for (int j = 0; j < 4; ++j) b[j] = Bs[kk][tx * 4 + j];
#pragma unroll
            for (int i = 0; i < 4; ++i)
#pragma unroll
                for (int j = 0; j < 4; ++j) acc[i][j] += a[i] * b[j];
        }
        __syncthreads();
        if (more) {
            writeAB();
            __syncthreads();
        }
    }
    // plain coalesced partial stores (no atomics)
    int c0 = col0 + tx * 4;
    float* Pz = P + (size_t)blockIdx.z * PROWS * PLD;
#pragma unroll
    for (int i = 0; i < 4; ++i) {
        int r = row0 + ty * 4 + i;
        if (r < M) {
            float* dstp = Pz + (size_t)r * PLD + c0;
            if (c0 + 3 < DIM) {
                float4 v = make_float4(acc[i][0], acc[i][1], acc[i][2], acc[i][3]);
                *reinterpret_cast<float4*>(dstp) = v;
            } else {
#pragma unroll
                for (int j = 0; j < 4; ++j)
                    if (c0 + j < DIM) dstp[j] = acc[i][j];
            }
        }
    }
}

// ---------------- reduce 16 partials -> xt ----------------
__global__ void k_reduce(const float* __restrict__ P, float* __restrict__ xt, int M) {
    int idx = blockIdx.x * 256 + threadIdx.x;
    if (idx >= M * DIM) return;
    int r = idx / DIM, o = idx - r * DIM;
    const float* p = P + (size_t)r * PLD + o;
    float s = 0.f;
#pragma unroll
    for (int z = 0; z < SPLITK; ++z) s += p[(size_t)z * PROWS * PLD];
    xt[idx] = s;
}

// ---------------- aggregation + bias, fused pooling score ----------------
__global__ void k_agg(const float* __restrict__ xt, const int* __restrict__ cnt,
                      const int* __restrict__ bucket, const int* __restrict__ srcArr,
                      const float* __restrict__ eattr, const int* __restrict__ newidx,
                      const float* __restrict__ bias, const float* __restrict__ w,
                      float* __restrict__ out, float* __restrict__ score) {
    __shared__ float alpha[MAXIN];
    __shared__ int sidx[MAXIN];
    __shared__ float red[256];
    __shared__ float red2[256];
    int n = blockIdx.x, t = threadIdx.x;
    int c = cnt[n]; if (c > MAXIN) c = MAXIN;
    float mysum = 0.f;
    for (int j = t; j < c; j += 256) {
        int e = bucket[(size_t)n * MAXIN + j];
        int s = srcArr[e];
        if (newidx) s = newidx[s];
        float ex = expf(eattr[e]);
        alpha[j] = ex;
        sidx[j] = s;
        mysum += ex;
    }
    red[t] = mysum;
    __syncthreads();
    for (int off = 128; off > 0; off >>= 1) {
        if (t < off) red[t] += red[t + off];
        __syncthreads();
    }
    const float eself = 2.718281828459045f;
    float inv = 1.f / (red[0] + eself);
    __syncthreads();
    for (int j = t; j < c; j += 256) alpha[j] *= inv;
    __syncthreads();
    float aself = eself * inv;
    float dotp = 0.f, wsq = 0.f;
    for (int o = t; o < DIM; o += 256) {
        float acc = bias[o] + aself * xt[(size_t)n * DIM + o];
        for (int j = 0; j < c; ++j) acc += alpha[j] * xt[(size_t)sidx[j] * DIM + o];
        out[(size_t)n * DIM + o] = acc;
        float wv = w[o];
        dotp += acc * wv;
        wsq += wv * wv;
    }
    red[t] = dotp; red2[t] = wsq;
    __syncthreads();
    for (int off = 128; off > 0; off >>= 1) {
        if (t < off) { red[t] += red[t + off]; red2[t] += red2[t + off]; }
        __syncthreads();
    }
    if (t == 0) score[n] = 1.f / (1.f + expf(-red[0] / sqrtf(red2[0])));
}

// ---------------- top-k rank + (level1) bucket2 build; also zeroes next accumulators ----------------
__global__ void k_topk(const float* __restrict__ score, int n_per, int k,
                       int* __restrict__ perm, int* __restrict__ newidx,
                       const int* __restrict__ src, const int* __restrict__ dst,
                       int* __restrict__ cnt2, int* __restrict__ bucket2,
                       float* __restrict__ fz1, int fn1,
                       float* __restrict__ fz2, int fn2) {
    __shared__ float s[NPG];
    __shared__ short nidxS[NPG];
    int g = blockIdx.x, t = threadIdx.x;     // 2 blocks x 384
    for (int i = t; i < n_per; i += 384) s[i] = score[g * n_per + i];
    if (cnt2) for (int i = t; i < k; i += 384) cnt2[g * k + i] = 0;
    if (fz1) for (int i = g * 384 + t; i < fn1; i += GG * 384) fz1[i] = 0.f;
    if (fz2) for (int i = g * 384 + t; i < fn2; i += GG * 384) fz2[i] = 0.f;
    __syncthreads();
    for (int i = t; i < n_per; i += 384) {
        float si = s[i];
        int r = 0;
        for (int j = 0; j < n_per; ++j) {
            float sj = s[j];
            r += (sj > si) || (sj == si && j < i);
        }
        int node = g * n_per + i;
        if (r < k) {
            perm[g * k + r] = node;
            newidx[node] = g * k + r;
            nidxS[i] = (short)(g * k + r);
        } else {
            newidx[node] = -1;
            nidxS[i] = -1;
        }
    }
    if (cnt2) {
        __syncthreads();
        int e0 = g * EPG;
        for (int e = e0 + t; e < e0 + EPG; e += 384) {
            int ns = nidxS[src[e] - g * n_per];
            int nd = nidxS[dst[e] - g * n_per];
            if (ns >= 0 && nd >= 0) {
                int slot = atomicAdd(&cnt2[nd], 1);
                if (slot < MAXIN) bucket2[(size_t)nd * MAXIN + slot] = e;
            }
        }
    }
}

// ---------------- gather: xnew (optional) + readout max/mean, column-parallel ----------------
__global__ void k_gather(const float* __restrict__ xv, const float* __restrict__ score,
                         const int* __restrict__ perm, int k,
                         float* __restrict__ xnew, float* __restrict__ z, int zbase) {
    int g = blockIdx.y;
    int o = blockIdx.x * 256 + threadIdx.x;
    if (o >= DIM) return;
    float mx = -3.4e38f, sm = 0.f;
    for (int r = 0; r < k; ++r) {
        int p = perm[g * k + r];
        float v = xv[(size_t)p * DIM + o] * score[p];
        if (xnew) xnew[(size_t)(g * k + r) * DIM + o] = v;
        mx = fmaxf(mx, v);
        sm += v;
    }
    z[(size_t)g * 1328 + zbase + o] = mx;
    z[(size_t)g * 1328 + zbase + DIM + o] = sm / (float)k;
}

// ---------------- fc1 partials ----------------
__global__ void k_fc1(const float* __restrict__ z, const float* __restrict__ W,
                      float* __restrict__ hacc) {
    __shared__ float zs[2][166];
    int t = threadIdx.x;                 // 128
    int j = blockIdx.x * 128 + t;
    int i0 = blockIdx.y * 166;
    for (int i = t; i < 166; i += 128) {
        zs[0][i] = z[i0 + i];
        zs[1][i] = z[1328 + i0 + i];
    }
    __syncthreads();
    if (j >= DIM) return;
    float a0 = 0.f, a1 = 0.f;
    for (int i = 0; i < 166; ++i) {
        float wv = W[(size_t)(i0 + i) * DIM + j];
        a0 += zs[0][i] * wv;
        a1 += zs[1][i] * wv;
    }
    atomicAdd(&hacc[j], a0);
    atomicAdd(&hacc[DIM + j], a1);
}

// ---------------- fc2 partials: BN1+relu on chunk, then partial fc2 ----------------
__global__ void k_fc2(const float* __restrict__ hacc, const float* __restrict__ fc1b,
                      const float* __restrict__ bn1g, const float* __restrict__ bn1b,
                      const float* __restrict__ W, float* __restrict__ f2acc) {
    __shared__ float z1s[2][83];
    int t = threadIdx.x;                 // 128
    int i0 = blockIdx.x * 83;
    if (t < 83) {
        int col = i0 + t;
        float a0 = hacc[col] + fc1b[col];
        float a1 = hacc[DIM + col] + fc1b[col];
        float m = 0.5f * (a0 + a1);
        float d0 = a0 - m, d1 = a1 - m;
        float v = 0.5f * (d0 * d0 + d1 * d1);
        float is = 1.f / sqrtf(v + 1e-5f);
        float gj = bn1g[col], bj = bn1b[col];
        z1s[0][t] = fmaxf(d0 * is * gj + bj, 0.f);
        z1s[1][t] = fmaxf(d1 * is * gj + bj, 0.f);
    }
    __syncthreads();
    float a0 = 0.f, a1 = 0.f;
    for (int i = 0; i < 83; ++i) {
        float wv = W[(size_t)(i0 + i) * DD3 + t];
        a0 += z1s[0][i] * wv;
        a1 += z1s[1][i] * wv;
    }
    atomicAdd(&f2acc[t], a0);
    atomicAdd(&f2acc[DD3 + t], a1);
}

// ---------------- final: BN2+relu+fc3 ----------------
__global__ void k_head3(const float* __restrict__ f2acc, const float* __restrict__ fc2b,
                        const float* __restrict__ bn2g, const float* __restrict__ bn2b,
                        const float* __restrict__ fc3W, const float* __restrict__ fc3b,
                        float* __restrict__ out) {
    __shared__ float z2s[2][DD3];
    int t = threadIdx.x;                 // 128
    {
        float a0 = f2acc[t] + fc2b[t];
        float a1 = f2acc[DD3 + t] + fc2b[t];
        float m = 0.5f * (a0 + a1);
        float d0 = a0 - m, d1 = a1 - m;
        float v = 0.5f * (d0 * d0 + d1 * d1);
        float is = 1.f / sqrtf(v + 1e-5f);
        float gj = bn2g[t], bj = bn2b[t];
        z2s[0][t] = fmaxf(d0 * is * gj + bj, 0.f);
        z2s[1][t] = fmaxf(d1 * is * gj + bj, 0.f);
    }
    __syncthreads();
    if (t < 4) {
        int g = t >> 1, c = t & 1;
        float acc = fc3b[c];
        for (int i = 0; i < DD3; ++i) acc += z2s[g][i] * fc3W[i * 2 + c];
        out[g * 2 + c] = acc;
    }
}

extern "C" void kernel_launch(void* const* d_in, const int* in_sizes, int n_in,
                              void* d_out, int out_size, void* d_ws, size_t ws_size,
                              hipStream_t stream) {
    (void)in_sizes; (void)n_in; (void)out_size; (void)ws_size;
    const float* x     = (const float*)d_in[0];
    const int*   eidx  = (const int*)d_in[1];
    const float* eattr = (const float*)d_in[3];
    const float* c1W1  = (const float*)d_in[6];
    const float* c1W2  = (const float*)d_in[7];
    const float* c1nb  = (const float*)d_in[8];
    const float* c1b   = (const float*)d_in[9];
    const float* p1w   = (const float*)d_in[10];
    const float* c2W1  = (const float*)d_in[11];
    const float* c2W2  = (const float*)d_in[12];
    const float* c2nb  = (const float*)d_in[13];
    const float* c2b   = (const float*)d_in[14];
    const float* p2w   = (const float*)d_in[15];
    const float* fc1W  = (const float*)d_in[16];
    const float* fc1b  = (const float*)d_in[17];
    const float* bn1g  = (const float*)d_in[18];
    const float* bn1b  = (const float*)d_in[19];
    const float* fc2W  = (const float*)d_in[20];
    const float* fc2b  = (const float*)d_in[21];
    const float* bn2g  = (const float*)d_in[22];
    const float* bn2b  = (const float*)d_in[23];
    const float* fc3W  = (const float*)d_in[24];
    const float* fc3b  = (const float*)d_in[25];

    const int* src = eidx;
    const int* dst = eidx + EE;

    char* w = (char*)d_ws;
    auto alloc = [&](size_t bytes) { void* p = (void*)w; w += ((bytes + 255) / 256) * 256; return p; };
    float* Pbuf    = (float*)alloc((size_t)SPLITK * PROWS * PLD * 4);   // 15.1 MB, reused by both convs
    int*   cnt1    = (int*)alloc(NN * 4);
    int*   bucket1 = (int*)alloc((size_t)NN * MAXIN * 4);
    float* xt1     = (float*)alloc((size_t)NN * DIM * 4);
    float* out1    = (float*)alloc((size_t)NN * DIM * 4);
    float* score1  = (float*)alloc(NN * 4);
    int*   perm1   = (int*)alloc(GG * KP1 * 4);
    int*   newidx1 = (int*)alloc(NN * 4);
    float* x1p     = (float*)alloc((size_t)GG * KP1 * DIM * 4);
    float* zbuf    = (float*)alloc(GG * 1328 * 4);
    int*   cnt2    = (int*)alloc(GG * KP1 * 4);
    int*   bucket2 = (int*)alloc((size_t)GG * KP1 * MAXIN * 4);
    float* xt2     = (float*)alloc((size_t)GG * KP1 * DIM * 4);
    float* out2    = (float*)alloc((size_t)GG * KP1 * DIM * 4);
    float* score2  = (float*)alloc(GG * KP1 * 4);
    int*   perm2   = (int*)alloc(GG * KP2 * 4);
    int*   newidx2 = (int*)alloc(GG * KP1 * 4);
    float* hacc    = (float*)alloc(2 * DIM * 4);
    float* f2acc   = (float*)alloc(2 * DD3 * 4);

    // ---- conv1 ----
    k_bucket1<<<GG, 384, 0, stream>>>(dst, cnt1, bucket1);
    k_gemm<<<dim3(6, 11, SPLITK), 256, 0, stream>>>(x, nullptr, c1W1, c1W2, c1nb, Pbuf, NN);
    k_reduce<<<(NN * DIM + 255) / 256, 256, 0, stream>>>(Pbuf, xt1, NN);
    k_agg<<<NN, 256, 0, stream>>>(xt1, cnt1, bucket1, src, eattr, nullptr, c1b, p1w, out1, score1);

    // ---- pool1 (+ bucket2 build + zero cnt2) ----
    k_topk<<<GG, 384, 0, stream>>>(score1, NPG, KP1, perm1, newidx1,
                                   src, dst, cnt2, bucket2,
                                   nullptr, 0, nullptr, 0);
    k_gather<<<dim3(2, GG), 256, 0, stream>>>(out1, score1, perm1, KP1, x1p, zbuf, 0);

    // ---- conv2 ----
    k_gemm<<<dim3(6, 6, SPLITK), 256, 0, stream>>>(x1p, perm1, c2W1, c2W2, c2nb, Pbuf, GG * KP1);
    k_reduce<<<(GG * KP1 * DIM + 255) / 256, 256, 0, stream>>>(Pbuf, xt2, GG * KP1);
    k_agg<<<GG * KP1, 256, 0, stream>>>(xt2, cnt2, bucket2, src, eattr, newidx1, c2b, p2w, out2, score2);

    // ---- pool2 (+ zero hacc/f2acc) ----
    k_topk<<<GG, 384, 0, stream>>>(score2, KP1, KP2, perm2, newidx2,
                                   nullptr, nullptr, nullptr, nullptr,
                                   hacc, 2 * DIM, f2acc, 2 * DD3);
    k_gather<<<dim3(2, GG), 256, 0, stream>>>(out2, score2, perm2, KP2, nullptr, zbuf, 664);

    // ---- head ----
    k_fc1<<<dim3(3, 8), 128, 0, stream>>>(zbuf, fc1W, hacc);
    k_fc2<<<4, 128, 0, stream>>>(hacc, fc1b, bn1g, bn1b, fc2W, f2acc);
    k_head3<<<1, 128, 0, stream>>>(f2acc, fc2b, bn2g, bn2b, fc3W, fc3b, (float*)d_out);
}

// Round 11
// 286.846 us; speedup vs baseline: 1.6425x; 1.2059x over previous
//
#include <hip/hip_runtime.h>
#include <hip/hip_bf16.h>
#include <math.h>

#define GG 2
#define NPG 332
#define NN 664
#define EE 21248
#define EPG 10624
#define KHD 6
#define KP1 166
#define KP2 83
#define DIM 332
#define DD3 128
#define MAXIN 128
#define KTOT 2324          // 7*332
#define W2ROWS 1992        // 6*332
#define PLD 336            // padded partial-C leading dim
#define PROWS 704          // padded partial-C rows

// ---------------- bucket build conv1: per-graph LDS counting ----------------
__global__ void k_bucket1(const int* __restrict__ dst, int* __restrict__ cnt, int* __restrict__ bucket) {
    __shared__ int lcnt[NPG];
    int g = blockIdx.x, t = threadIdx.x;        // 2 blocks x 384
    for (int i = t; i < NPG; i += 384) lcnt[i] = 0;
    __syncthreads();
    int e0 = g * EPG;
    for (int e = e0 + t; e < e0 + EPG; e += 384) {
        int dl = dst[e] - g * NPG;
        int slot = atomicAdd(&lcnt[dl], 1);
        if (slot < MAXIN) bucket[(size_t)(g * NPG + dl) * MAXIN + slot] = e;
    }
    __syncthreads();
    for (int i = t; i < NPG; i += 384) cnt[g * NPG + i] = lcnt[i];
}

// ---------------- GEMM, fused A-build, reg-prefetch, PLAIN partial stores ----------------
#define BM 64
#define BN 64
#define BK 16
#define SPLITK 16

__global__ __launch_bounds__(256) void k_gemm(const float* __restrict__ X,
                                              const int* __restrict__ perm,
                                              const float* __restrict__ W1,
                                              const float* __restrict__ W2,
                                              const float* __restrict__ nb,
                                              float* __restrict__ P, int M) {
    __shared__ float As[BK][BM + 4];
    __shared__ float Bs[BK][BN];
    __shared__ float hs[BM][8];
    int tid = threadIdx.x;
    int tx = tid & 15, ty = tid >> 4;
    int col0 = blockIdx.x * BN, row0 = blockIdx.y * BM;
    if (tid < BM) {
        int r = row0 + tid;
        int roi = (r < M) ? ((perm ? perm[r] : r) % DIM) : 0;
        bool ok = r < M;
#pragma unroll
        for (int k = 0; k < 6; ++k)
            hs[tid][k] = ok ? fmaxf(W1[roi * KHD + k], 0.f) : 0.f;
        hs[tid][6] = ok ? 1.f : 0.f;
        hs[tid][7] = 0.f;
    }
    const int kc = (KTOT + SPLITK - 1) / SPLITK;    // 146
    int k0 = blockIdx.z * kc;
    int k1 = k0 + kc; if (k1 > KTOT) k1 = KTOT;
    __syncthreads();                                 // hs ready

    int kkA = tid & 15;          // A: k within tile
    int m0A = tid >> 4;          // A: row group 0..15
    int nB  = tid & 63;          // B: col within tile
    int kB0 = tid >> 6;          // B: k group 0..3

    float aReg[4], bReg[4];
    auto loadAB = [&](int kb) {
        {
            int kg = kb + kkA;
            bool kok = kg < k1;
            int kch = kg / DIM;
            int i = kg - kch * DIM;
#pragma unroll
            for (int mi = 0; mi < 4; ++mi) {
                int mm = m0A + mi * 16;
                int r = row0 + mm;
                aReg[mi] = (kok && r < M) ? hs[mm][kch] * X[(size_t)r * DIM + i] : 0.f;
            }
        }
        {
            int c = col0 + nB;
#pragma unroll
            for (int ki = 0; ki < 4; ++ki) {
                int r = kb + kB0 + ki * 4;
                float v = 0.f;
                if (r < k1 && c < DIM) {
                    const float* Brow = (r < W2ROWS) ? (W2 + (size_t)r * DIM)
                                                     : (nb + (size_t)(r - W2ROWS) * DIM);
                    v = Brow[c];
                }
                bReg[ki] = v;
            }
        }
    };
    auto writeAB = [&]() {
#pragma unroll
        for (int mi = 0; mi < 4; ++mi) As[kkA][m0A + mi * 16] = aReg[mi];
#pragma unroll
        for (int ki = 0; ki < 4; ++ki) Bs[kB0 + ki * 4][nB] = bReg[ki];
    };

    float acc[4][4] = {};
    loadAB(k0);
    writeAB();
    __syncthreads();
    for (int kb = k0; kb < k1; kb += BK) {
        int kn = kb + BK;
        bool more = kn < k1;
        if (more) loadAB(kn);            // prefetch in flight during compute
#pragma unroll
        for (int kk = 0; kk < BK; ++kk) {
            float a[4], b[4];
#pragma unroll
            for (int i = 0; i < 4; ++i) a[i] = As[kk][ty * 4 + i];
#pragma unroll
            for (int j = 0; j < 4; ++j) b[j] = Bs[kk][tx * 4 + j];
#pragma unroll
            for (int i = 0; i < 4; ++i)
#pragma unroll
                for (int j = 0; j < 4; ++j) acc[i][j] += a[i] * b[j];
        }
        __syncthreads();
        if (more) {
            writeAB();
            __syncthreads();
        }
    }
    // plain coalesced partial stores (no atomics)
    int c0 = col0 + tx * 4;
    float* Pz = P + (size_t)blockIdx.z * PROWS * PLD;
#pragma unroll
    for (int i = 0; i < 4; ++i) {
        int r = row0 + ty * 4 + i;
        if (r < M) {
            float* dstp = Pz + (size_t)r * PLD + c0;
            if (c0 + 3 < DIM) {
                float4 v = make_float4(acc[i][0], acc[i][1], acc[i][2], acc[i][3]);
                *reinterpret_cast<float4*>(dstp) = v;
            } else {
#pragma unroll
                for (int j = 0; j < 4; ++j)
                    if (c0 + j < DIM) dstp[j] = acc[i][j];
            }
        }
    }
}

// ---------------- reduce 16 partials -> xt ----------------
__global__ void k_reduce(const float* __restrict__ P, float* __restrict__ xt, int M) {
    int idx = blockIdx.x * 256 + threadIdx.x;
    if (idx >= M * DIM) return;
    int r = idx / DIM, o = idx - r * DIM;
    const float* p = P + (size_t)r * PLD + o;
    float s = 0.f;
#pragma unroll
    for (int z = 0; z < SPLITK; ++z) s += p[(size_t)z * PROWS * PLD];
    xt[idx] = s;
}

// ---------------- aggregation + bias, fused pooling score ----------------
__global__ void k_agg(const float* __restrict__ xt, const int* __restrict__ cnt,
                      const int* __restrict__ bucket, const int* __restrict__ srcArr,
                      const float* __restrict__ eattr, const int* __restrict__ newidx,
                      const float* __restrict__ bias, const float* __restrict__ w,
                      float* __restrict__ out, float* __restrict__ score) {
    __shared__ float alpha[MAXIN];
    __shared__ int sidx[MAXIN];
    __shared__ float red[256];
    __shared__ float red2[256];
    int n = blockIdx.x, t = threadIdx.x;
    int c = cnt[n]; if (c > MAXIN) c = MAXIN;
    float mysum = 0.f;
    for (int j = t; j < c; j += 256) {
        int e = bucket[(size_t)n * MAXIN + j];
        int s = srcArr[e];
        if (newidx) s = newidx[s];
        float ex = expf(eattr[e]);
        alpha[j] = ex;
        sidx[j] = s;
        mysum += ex;
    }
    red[t] = mysum;
    __syncthreads();
    for (int off = 128; off > 0; off >>= 1) {
        if (t < off) red[t] += red[t + off];
        __syncthreads();
    }
    const float eself = 2.718281828459045f;
    float inv = 1.f / (red[0] + eself);
    __syncthreads();
    for (int j = t; j < c; j += 256) alpha[j] *= inv;
    __syncthreads();
    float aself = eself * inv;
    float dotp = 0.f, wsq = 0.f;
    for (int o = t; o < DIM; o += 256) {
        float acc = bias[o] + aself * xt[(size_t)n * DIM + o];
        for (int j = 0; j < c; ++j) acc += alpha[j] * xt[(size_t)sidx[j] * DIM + o];
        out[(size_t)n * DIM + o] = acc;
        float wv = w[o];
        dotp += acc * wv;
        wsq += wv * wv;
    }
    red[t] = dotp; red2[t] = wsq;
    __syncthreads();
    for (int off = 128; off > 0; off >>= 1) {
        if (t < off) { red[t] += red[t + off]; red2[t] += red2[t + off]; }
        __syncthreads();
    }
    if (t == 0) score[n] = 1.f / (1.f + expf(-red[0] / sqrtf(red2[0])));
}

// ---------------- top-k rank + (level1) bucket2 build; also zeroes next accumulators ----------------
__global__ void k_topk(const float* __restrict__ score, int n_per, int k,
                       int* __restrict__ perm, int* __restrict__ newidx,
                       const int* __restrict__ src, const int* __restrict__ dst,
                       int* __restrict__ cnt2, int* __restrict__ bucket2,
                       float* __restrict__ fz1, int fn1,
                       float* __restrict__ fz2, int fn2) {
    __shared__ float s[NPG];
    __shared__ short nidxS[NPG];
    int g = blockIdx.x, t = threadIdx.x;     // 2 blocks x 384
    for (int i = t; i < n_per; i += 384) s[i] = score[g * n_per + i];
    if (cnt2) for (int i = t; i < k; i += 384) cnt2[g * k + i] = 0;
    if (fz1) for (int i = g * 384 + t; i < fn1; i += GG * 384) fz1[i] = 0.f;
    if (fz2) for (int i = g * 384 + t; i < fn2; i += GG * 384) fz2[i] = 0.f;
    __syncthreads();
    for (int i = t; i < n_per; i += 384) {
        float si = s[i];
        int r = 0;
        for (int j = 0; j < n_per; ++j) {
            float sj = s[j];
            r += (sj > si) || (sj == si && j < i);
        }
        int node = g * n_per + i;
        if (r < k) {
            perm[g * k + r] = node;
            newidx[node] = g * k + r;
            nidxS[i] = (short)(g * k + r);
        } else {
            newidx[node] = -1;
            nidxS[i] = -1;
        }
    }
    if (cnt2) {
        __syncthreads();
        int e0 = g * EPG;
        for (int e = e0 + t; e < e0 + EPG; e += 384) {
            int ns = nidxS[src[e] - g * n_per];
            int nd = nidxS[dst[e] - g * n_per];
            if (ns >= 0 && nd >= 0) {
                int slot = atomicAdd(&cnt2[nd], 1);
                if (slot < MAXIN) bucket2[(size_t)nd * MAXIN + slot] = e;
            }
        }
    }
}

// ---------------- gather v2: LDS-staged perm/score, 4 r-lanes x 64 cols ----------------
__global__ void k_gather(const float* __restrict__ xv, const float* __restrict__ score,
                         const int* __restrict__ perm, int k,
                         float* __restrict__ xnew, float* __restrict__ z, int zbase) {
    __shared__ int   pS[KP1];
    __shared__ float sS[KP1];
    __shared__ float mxs[4][64];
    __shared__ float sms[4][64];
    int g = blockIdx.y;
    int t = threadIdx.x;                 // 256 = 4 r-lanes x 64 cols
    for (int i = t; i < k; i += 256) {
        int p = perm[g * k + i];
        pS[i] = p;
        sS[i] = score[p];
    }
    __syncthreads();
    int oc = t & 63, rl = t >> 6;
    int o = blockIdx.x * 64 + oc;
    float mx = -3.4e38f, sm = 0.f;
    if (o < DIM) {
        int r = rl;
        // 2-way unrolled independent iterations for memory-level parallelism
        for (; r + 4 < k; r += 8) {
            float v0 = xv[(size_t)pS[r] * DIM + o] * sS[r];
            float v1 = xv[(size_t)pS[r + 4] * DIM + o] * sS[r + 4];
            if (xnew) {
                xnew[(size_t)(g * k + r) * DIM + o] = v0;
                xnew[(size_t)(g * k + r + 4) * DIM + o] = v1;
            }
            mx = fmaxf(mx, fmaxf(v0, v1));
            sm += v0 + v1;
        }
        for (; r < k; r += 4) {
            float v = xv[(size_t)pS[r] * DIM + o] * sS[r];
            if (xnew) xnew[(size_t)(g * k + r) * DIM + o] = v;
            mx = fmaxf(mx, v);
            sm += v;
        }
    }
    mxs[rl][oc] = mx;
    sms[rl][oc] = sm;
    __syncthreads();
    if (rl == 0 && o < DIM) {
        float M = fmaxf(fmaxf(mxs[0][oc], mxs[1][oc]), fmaxf(mxs[2][oc], mxs[3][oc]));
        float S = sms[0][oc] + sms[1][oc] + sms[2][oc] + sms[3][oc];
        z[(size_t)g * 1328 + zbase + o] = M;
        z[(size_t)g * 1328 + zbase + DIM + o] = S / (float)k;
    }
}

// ---------------- fc1 partials ----------------
__global__ void k_fc1(const float* __restrict__ z, const float* __restrict__ W,
                      float* __restrict__ hacc) {
    __shared__ float zs[2][166];
    int t = threadIdx.x;                 // 128
    int j = blockIdx.x * 128 + t;
    int i0 = blockIdx.y * 166;
    for (int i = t; i < 166; i += 128) {
        zs[0][i] = z[i0 + i];
        zs[1][i] = z[1328 + i0 + i];
    }
    __syncthreads();
    if (j >= DIM) return;
    float a0 = 0.f, a1 = 0.f;
    for (int i = 0; i < 166; ++i) {
        float wv = W[(size_t)(i0 + i) * DIM + j];
        a0 += zs[0][i] * wv;
        a1 += zs[1][i] * wv;
    }
    atomicAdd(&hacc[j], a0);
    atomicAdd(&hacc[DIM + j], a1);
}

// ---------------- fc2 partials: BN1+relu on chunk, then partial fc2 ----------------
__global__ void k_fc2(const float* __restrict__ hacc, const float* __restrict__ fc1b,
                      const float* __restrict__ bn1g, const float* __restrict__ bn1b,
                      const float* __restrict__ W, float* __restrict__ f2acc) {
    __shared__ float z1s[2][83];
    int t = threadIdx.x;                 // 128
    int i0 = blockIdx.x * 83;
    if (t < 83) {
        int col = i0 + t;
        float a0 = hacc[col] + fc1b[col];
        float a1 = hacc[DIM + col] + fc1b[col];
        float m = 0.5f * (a0 + a1);
        float d0 = a0 - m, d1 = a1 - m;
        float v = 0.5f * (d0 * d0 + d1 * d1);
        float is = 1.f / sqrtf(v + 1e-5f);
        float gj = bn1g[col], bj = bn1b[col];
        z1s[0][t] = fmaxf(d0 * is * gj + bj, 0.f);
        z1s[1][t] = fmaxf(d1 * is * gj + bj, 0.f);
    }
    __syncthreads();
    float a0 = 0.f, a1 = 0.f;
    for (int i = 0; i < 83; ++i) {
        float wv = W[(size_t)(i0 + i) * DD3 + t];
        a0 += z1s[0][i] * wv;
        a1 += z1s[1][i] * wv;
    }
    atomicAdd(&f2acc[t], a0);
    atomicAdd(&f2acc[DD3 + t], a1);
}

// ---------------- final: BN2+relu+fc3 ----------------
__global__ void k_head3(const float* __restrict__ f2acc, const float* __restrict__ fc2b,
                        const float* __restrict__ bn2g, const float* __restrict__ bn2b,
                        const float* __restrict__ fc3W, const float* __restrict__ fc3b,
                        float* __restrict__ out) {
    __shared__ float z2s[2][DD3];
    int t = threadIdx.x;                 // 128
    {
        float a0 = f2acc[t] + fc2b[t];
        float a1 = f2acc[DD3 + t] + fc2b[t];
        float m = 0.5f * (a0 + a1);
        float d0 = a0 - m, d1 = a1 - m;
        float v = 0.5f * (d0 * d0 + d1 * d1);
        float is = 1.f / sqrtf(v + 1e-5f);
        float gj = bn2g[t], bj = bn2b[t];
        z2s[0][t] = fmaxf(d0 * is * gj + bj, 0.f);
        z2s[1][t] = fmaxf(d1 * is * gj + bj, 0.f);
    }
    __syncthreads();
    if (t < 4) {
        int g = t >> 1, c = t & 1;
        float acc = fc3b[c];
        for (int i = 0; i < DD3; ++i) acc += z2s[g][i] * fc3W[i * 2 + c];
        out[g * 2 + c] = acc;
    }
}

extern "C" void kernel_launch(void* const* d_in, const int* in_sizes, int n_in,
                              void* d_out, int out_size, void* d_ws, size_t ws_size,
                              hipStream_t stream) {
    (void)in_sizes; (void)n_in; (void)out_size; (void)ws_size;
    const float* x     = (const float*)d_in[0];
    const int*   eidx  = (const int*)d_in[1];
    const float* eattr = (const float*)d_in[3];
    const float* c1W1  = (const float*)d_in[6];
    const float* c1W2  = (const float*)d_in[7];
    const float* c1nb  = (const float*)d_in[8];
    const float* c1b   = (const float*)d_in[9];
    const float* p1w   = (const float*)d_in[10];
    const float* c2W1  = (const float*)d_in[11];
    const float* c2W2  = (const float*)d_in[12];
    const float* c2nb  = (const float*)d_in[13];
    const float* c2b   = (const float*)d_in[14];
    const float* p2w   = (const float*)d_in[15];
    const float* fc1W  = (const float*)d_in[16];
    const float* fc1b  = (const float*)d_in[17];
    const float* bn1g  = (const float*)d_in[18];
    const float* bn1b  = (const float*)d_in[19];
    const float* fc2W  = (const float*)d_in[20];
    const float* fc2b  = (const float*)d_in[21];
    const float* bn2g  = (const float*)d_in[22];
    const float* bn2b  = (const float*)d_in[23];
    const float* fc3W  = (const float*)d_in[24];
    const float* fc3b  = (const float*)d_in[25];

    const int* src = eidx;
    const int* dst = eidx + EE;

    char* w = (char*)d_ws;
    auto alloc = [&](size_t bytes) { void* p = (void*)w; w += ((bytes + 255) / 256) * 256; return p; };
    float* Pbuf    = (float*)alloc((size_t)SPLITK * PROWS * PLD * 4);   // 15.1 MB, reused by both convs
    int*   cnt1    = (int*)alloc(NN * 4);
    int*   bucket1 = (int*)alloc((size_t)NN * MAXIN * 4);
    float* xt1     = (float*)alloc((size_t)NN * DIM * 4);
    float* out1    = (float*)alloc((size_t)NN * DIM * 4);
    float* score1  = (float*)alloc(NN * 4);
    int*   perm1   = (int*)alloc(GG * KP1 * 4);
    int*   newidx1 = (int*)alloc(NN * 4);
    float* x1p     = (float*)alloc((size_t)GG * KP1 * DIM * 4);
    float* zbuf    = (float*)alloc(GG * 1328 * 4);
    int*   cnt2    = (int*)alloc(GG * KP1 * 4);
    int*   bucket2 = (int*)alloc((size_t)GG * KP1 * MAXIN * 4);
    float* xt2     = (float*)alloc((size_t)GG * KP1 * DIM * 4);
    float* out2    = (float*)alloc((size_t)GG * KP1 * DIM * 4);
    float* score2  = (float*)alloc(GG * KP1 * 4);
    int*   perm2   = (int*)alloc(GG * KP2 * 4);
    int*   newidx2 = (int*)alloc(GG * KP1 * 4);
    float* hacc    = (float*)alloc(2 * DIM * 4);
    float* f2acc   = (float*)alloc(2 * DD3 * 4);

    // ---- conv1 ----
    k_bucket1<<<GG, 384, 0, stream>>>(dst, cnt1, bucket1);
    k_gemm<<<dim3(6, 11, SPLITK), 256, 0, stream>>>(x, nullptr, c1W1, c1W2, c1nb, Pbuf, NN);
    k_reduce<<<(NN * DIM + 255) / 256, 256, 0, stream>>>(Pbuf, xt1, NN);
    k_agg<<<NN, 256, 0, stream>>>(xt1, cnt1, bucket1, src, eattr, nullptr, c1b, p1w, out1, score1);

    // ---- pool1 (+ bucket2 build + zero cnt2) ----
    k_topk<<<GG, 384, 0, stream>>>(score1, NPG, KP1, perm1, newidx1,
                                   src, dst, cnt2, bucket2,
                                   nullptr, 0, nullptr, 0);
    k_gather<<<dim3(6, GG), 256, 0, stream>>>(out1, score1, perm1, KP1, x1p, zbuf, 0);

    // ---- conv2 ----
    k_gemm<<<dim3(6, 6, SPLITK), 256, 0, stream>>>(x1p, perm1, c2W1, c2W2, c2nb, Pbuf, GG * KP1);
    k_reduce<<<(GG * KP1 * DIM + 255) / 256, 256, 0, stream>>>(Pbuf, xt2, GG * KP1);
    k_agg<<<GG * KP1, 256, 0, stream>>>(xt2, cnt2, bucket2, src, eattr, newidx1, c2b, p2w, out2, score2);

    // ---- pool2 (+ zero hacc/f2acc) ----
    k_topk<<<GG, 384, 0, stream>>>(score2, KP1, KP2, perm2, newidx2,
                                   nullptr, nullptr, nullptr, nullptr,
                                   hacc, 2 * DIM, f2acc, 2 * DD3);
    k_gather<<<dim3(6, GG), 256, 0, stream>>>(out2, score2, perm2, KP2, nullptr, zbuf, 664);

    // ---- head ----
    k_fc1<<<dim3(3, 8), 128, 0, stream>>>(zbuf, fc1W, hacc);
    k_fc2<<<4, 128, 0, stream>>>(hacc, fc1b, bn1g, bn1b, fc2W, f2acc);
    k_head3<<<1, 128, 0, stream>>>(f2acc, fc2b, bn2g, bn2b, fc3W, fc3b, (float*)d_out);
}